// Round 1
// baseline (669.127 us; speedup 1.0000x reference)
//
#include <hip/hip_runtime.h>
#include <cstddef>

#define LEN    1024
#define DIN    512
#define NHEAD  8
#define HDIM   64
#define BATCH  8

// ---------------------------------------------------------------------------
// Kernel A: fused projection GEMM.  C = X @ W, X:[8192,512], W:[512,512].
// blockIdx.z selects (Q_seq,WQ)->q | (K_seq,WK)->k | (V_seq,WV)->v.
// Output written transposed to [B, H, L, D] so the attention kernel reads
// contiguous 64-float rows per (b,h,l).
// Tile: 64x64, BK=16, 256 threads, 4x4 micro-tile per thread.
// ---------------------------------------------------------------------------
__global__ __launch_bounds__(256)
void proj_kernel(const float* __restrict__ Qin, const float* __restrict__ Kin,
                 const float* __restrict__ Vin, const float* __restrict__ WQ,
                 const float* __restrict__ WK, const float* __restrict__ WV,
                 float* __restrict__ qo, float* __restrict__ ko,
                 float* __restrict__ vo)
{
    __shared__ float As[16][68];   // [k][m], padded
    __shared__ float Bs[16][68];   // [k][n], padded

    const int z = blockIdx.z;
    const float* X = (z == 0) ? Qin : (z == 1) ? Kin : Vin;
    const float* W = (z == 0) ? WQ  : (z == 1) ? WK  : WV;
    float* out     = (z == 0) ? qo  : (z == 1) ? ko  : vo;

    const int tid = threadIdx.x;
    const int tx  = tid & 15;        // 0..15 -> n quad
    const int ty  = tid >> 4;        // 0..15 -> m quad
    const int h   = blockIdx.x;      // 0..7, n0 = h*64
    const int m0  = blockIdx.y * 64;

    // staging indices
    const int arow  = tid >> 2;          // 0..63
    const int acol4 = (tid & 3) << 2;    // 0,4,8,12
    const int brow  = tid >> 4;          // 0..15
    const int bcol4 = (tid & 15) << 2;   // 0..60

    const float* Xp = X + (size_t)(m0 + arow) * DIN + acol4;
    const float* Wp = W + (size_t)brow * DIN + h * 64 + bcol4;

    float acc[4][4] = {};

    for (int k0 = 0; k0 < DIN; k0 += 16) {
        float4 av = *(const float4*)(Xp + k0);
        float4 bv = *(const float4*)(Wp + (size_t)k0 * DIN);
        __syncthreads();                       // previous micro-loop done
        As[acol4 + 0][arow] = av.x;            // transpose scatter (2-way: free)
        As[acol4 + 1][arow] = av.y;
        As[acol4 + 2][arow] = av.z;
        As[acol4 + 3][arow] = av.w;
        *(float4*)&Bs[brow][bcol4] = bv;
        __syncthreads();
        #pragma unroll
        for (int kk = 0; kk < 16; ++kk) {
            float4 a = *(const float4*)&As[kk][ty * 4];
            float4 b = *(const float4*)&Bs[kk][tx * 4];
            float ar[4] = {a.x, a.y, a.z, a.w};
            float br[4] = {b.x, b.y, b.z, b.w};
            #pragma unroll
            for (int i = 0; i < 4; ++i)
                #pragma unroll
                for (int j = 0; j < 4; ++j)
                    acc[i][j] += ar[i] * br[j];
        }
    }

    // store to [B, H, L, D]; n0 = h*64 so d = tx*4
    #pragma unroll
    for (int i = 0; i < 4; ++i) {
        int m = m0 + ty * 4 + i;
        int b = m >> 10;
        int l = m & 1023;
        float4 st = make_float4(acc[i][0], acc[i][1], acc[i][2], acc[i][3]);
        *(float4*)&out[((size_t)(b * NHEAD + h) * LEN + l) * HDIM + tx * 4] = st;
    }
}

// ---------------------------------------------------------------------------
// Kernel B: causal flash-style attention, fp32 throughout.
// One block per (b*h, 32-query tile).  256 threads: tx=tid&15 (4 cols/dims),
// ty=tid>>4 (2 rows).  K stored transposed in LDS (Kt[kdim][key]) so the
// S micro-loop does conflict-free b128 reads.
// ---------------------------------------------------------------------------
__global__ __launch_bounds__(256)
void attn_kernel(const float* __restrict__ q, const float* __restrict__ k,
                 const float* __restrict__ v, float* __restrict__ out)
{
    __shared__ float Qs[32][68];   // [query][dim]
    __shared__ float Kt[64][68];   // [dim][key]  (transposed)
    __shared__ float Vs[64][68];   // [key][dim]
    __shared__ float Ps[32][68];   // [query][key]
    __shared__ float red[32][16];

    const int tid = threadIdx.x;
    const int tx  = tid & 15;
    const int ty  = tid >> 4;
    const int qb  = blockIdx.x;          // 0..31
    const int bh  = blockIdx.y;          // 0..63
    const int q0  = qb * 32;

    const float* qbase = q + (size_t)bh * LEN * HDIM;
    const float* kbase = k + (size_t)bh * LEN * HDIM;
    const float* vbase = v + (size_t)bh * LEN * HDIM;

    // load Q tile (32x64 = 512 float4, 2 per thread)
    #pragma unroll
    for (int e = 0; e < 2; ++e) {
        int f  = e * 256 + tid;
        int r  = f >> 4;
        int c4 = (f & 15) << 2;
        *(float4*)&Qs[r][c4] =
            *(const float4*)&qbase[(size_t)(q0 + r) * HDIM + c4];
    }

    float m_i[2], l_i[2], acc[2][4];
    #pragma unroll
    for (int i = 0; i < 2; ++i) {
        m_i[i] = -1e30f;
        l_i[i] = 0.f;
        #pragma unroll
        for (int j = 0; j < 4; ++j) acc[i][j] = 0.f;
    }

    const int r0 = ty * 2;
    const int jend = (q0 + 31) >> 6;

    for (int jb = 0; jb <= jend; ++jb) {
        __syncthreads();  // prev iter's Kt/Vs/Ps reads done; also fences Q load
        // stage K (transposed) and V: 64x64 each, 4 float4/thread each
        #pragma unroll
        for (int e = 0; e < 4; ++e) {
            int f  = e * 256 + tid;
            int r  = f >> 4;
            int c4 = (f & 15) << 2;
            float4 kv = *(const float4*)&kbase[(size_t)(jb * 64 + r) * HDIM + c4];
            Kt[c4 + 0][r] = kv.x;
            Kt[c4 + 1][r] = kv.y;
            Kt[c4 + 2][r] = kv.z;
            Kt[c4 + 3][r] = kv.w;
            *(float4*)&Vs[r][c4] =
                *(const float4*)&vbase[(size_t)(jb * 64 + r) * HDIM + c4];
        }
        __syncthreads();

        // S = Q K^T * 0.125 ; rows r0+i, cols tx*4+j
        float s[2][4] = {};
        #pragma unroll
        for (int kk = 0; kk < 64; kk += 4) {
            float4 q0v = *(const float4*)&Qs[r0 + 0][kk];
            float4 q1v = *(const float4*)&Qs[r0 + 1][kk];
            float4 kv0 = *(const float4*)&Kt[kk + 0][tx * 4];
            float4 kv1 = *(const float4*)&Kt[kk + 1][tx * 4];
            float4 kv2 = *(const float4*)&Kt[kk + 2][tx * 4];
            float4 kv3 = *(const float4*)&Kt[kk + 3][tx * 4];
            s[0][0] += q0v.x*kv0.x + q0v.y*kv1.x + q0v.z*kv2.x + q0v.w*kv3.x;
            s[0][1] += q0v.x*kv0.y + q0v.y*kv1.y + q0v.z*kv2.y + q0v.w*kv3.y;
            s[0][2] += q0v.x*kv0.z + q0v.y*kv1.z + q0v.z*kv2.z + q0v.w*kv3.z;
            s[0][3] += q0v.x*kv0.w + q0v.y*kv1.w + q0v.z*kv2.w + q0v.w*kv3.w;
            s[1][0] += q1v.x*kv0.x + q1v.y*kv1.x + q1v.z*kv2.x + q1v.w*kv3.x;
            s[1][1] += q1v.x*kv0.y + q1v.y*kv1.y + q1v.z*kv2.y + q1v.w*kv3.y;
            s[1][2] += q1v.x*kv0.z + q1v.y*kv1.z + q1v.z*kv2.z + q1v.w*kv3.z;
            s[1][3] += q1v.x*kv0.w + q1v.y*kv1.w + q1v.z*kv2.w + q1v.w*kv3.w;
        }
        // scale + causal mask
        #pragma unroll
        for (int i = 0; i < 2; ++i)
            #pragma unroll
            for (int j = 0; j < 4; ++j) {
                s[i][j] *= 0.125f;
                if (jb * 64 + tx * 4 + j > q0 + r0 + i) s[i][j] = -1e30f;
            }

        // row-max reduction across the 16 tx threads of each row
        #pragma unroll
        for (int i = 0; i < 2; ++i) {
            float lm = fmaxf(fmaxf(s[i][0], s[i][1]), fmaxf(s[i][2], s[i][3]));
            red[r0 + i][tx] = lm;
        }
        __syncthreads();
        float mnew[2], alpha[2];
        #pragma unroll
        for (int i = 0; i < 2; ++i) {
            float mv = m_i[i];
            #pragma unroll
            for (int t = 0; t < 16; ++t) mv = fmaxf(mv, red[r0 + i][t]);
            mnew[i]  = mv;
            alpha[i] = __expf(m_i[i] - mv);
            m_i[i]   = mv;
        }
        __syncthreads();  // red re-use fence

        // p = exp(s - mnew), write to Ps, partial row sums
        #pragma unroll
        for (int i = 0; i < 2; ++i) {
            float ps = 0.f;
            #pragma unroll
            for (int j = 0; j < 4; ++j) {
                float p = __expf(s[i][j] - mnew[i]);
                Ps[r0 + i][tx * 4 + j] = p;
                ps += p;
            }
            red[r0 + i][tx] = ps;
        }
        __syncthreads();
        #pragma unroll
        for (int i = 0; i < 2; ++i) {
            float rs = 0.f;
            #pragma unroll
            for (int t = 0; t < 16; ++t) rs += red[r0 + i][t];
            l_i[i] = l_i[i] * alpha[i] + rs;
            #pragma unroll
            for (int j = 0; j < 4; ++j) acc[i][j] *= alpha[i];
        }

        // O += P V : dims d = tx*4+j
        #pragma unroll
        for (int kk = 0; kk < 64; kk += 4) {
            float4 p0 = *(const float4*)&Ps[r0 + 0][kk];
            float4 p1 = *(const float4*)&Ps[r0 + 1][kk];
            float4 v0 = *(const float4*)&Vs[kk + 0][tx * 4];
            float4 v1 = *(const float4*)&Vs[kk + 1][tx * 4];
            float4 v2 = *(const float4*)&Vs[kk + 2][tx * 4];
            float4 v3 = *(const float4*)&Vs[kk + 3][tx * 4];
            acc[0][0] += p0.x*v0.x + p0.y*v1.x + p0.z*v2.x + p0.w*v3.x;
            acc[0][1] += p0.x*v0.y + p0.y*v1.y + p0.z*v2.y + p0.w*v3.y;
            acc[0][2] += p0.x*v0.z + p0.y*v1.z + p0.z*v2.z + p0.w*v3.z;
            acc[0][3] += p0.x*v0.w + p0.y*v1.w + p0.z*v2.w + p0.w*v3.w;
            acc[1][0] += p1.x*v0.x + p1.y*v1.x + p1.z*v2.x + p1.w*v3.x;
            acc[1][1] += p1.x*v0.y + p1.y*v1.y + p1.z*v2.y + p1.w*v3.y;
            acc[1][2] += p1.x*v0.z + p1.y*v1.z + p1.z*v2.z + p1.w*v3.z;
            acc[1][3] += p1.x*v0.w + p1.y*v1.w + p1.z*v2.w + p1.w*v3.w;
        }
    }

    // epilogue: divide by l, write [B, L, H*D]
    const int b = bh >> 3;
    const int h = bh & 7;
    #pragma unroll
    for (int i = 0; i < 2; ++i) {
        int l = q0 + r0 + i;
        float inv = 1.0f / l_i[i];
        float4 o = make_float4(acc[i][0] * inv, acc[i][1] * inv,
                               acc[i][2] * inv, acc[i][3] * inv);
        *(float4*)&out[((size_t)b * LEN + l) * (NHEAD * HDIM) + h * 64 + tx * 4] = o;
    }
}

// ---------------------------------------------------------------------------
extern "C" void kernel_launch(void* const* d_in, const int* in_sizes, int n_in,
                              void* d_out, int out_size, void* d_ws, size_t ws_size,
                              hipStream_t stream)
{
    const float* Qin = (const float*)d_in[0];
    const float* Kin = (const float*)d_in[1];
    const float* Vin = (const float*)d_in[2];
    const float* WQ  = (const float*)d_in[3];
    const float* WK  = (const float*)d_in[4];
    const float* WV  = (const float*)d_in[5];

    float* ws = (float*)d_ws;
    const size_t per = (size_t)BATCH * NHEAD * LEN * HDIM;  // 4,194,304 floats
    float* qp = ws;
    float* kp = ws + per;
    float* vp = ws + 2 * per;

    dim3 pgrid(NHEAD, (BATCH * LEN) / 64, 3);   // 8 x 128 x 3
    proj_kernel<<<pgrid, 256, 0, stream>>>(Qin, Kin, Vin, WQ, WK, WV, qp, kp, vp);

    dim3 agrid(LEN / 32, BATCH * NHEAD);        // 32 x 64
    attn_kernel<<<agrid, 256, 0, stream>>>(qp, kp, vp, (float*)d_out);
}

// Round 2
// 225.815 us; speedup vs baseline: 2.9632x; 2.9632x over previous
//
#include <hip/hip_runtime.h>
#include <cstddef>

#define LEN    1024
#define DIN    512
#define NHEAD  8
#define HDIM   64
#define BATCH  8

typedef __attribute__((ext_vector_type(8))) short  short8;
typedef __attribute__((ext_vector_type(4))) float  f32x4;

#define MFMA16(a, b, c) __builtin_amdgcn_mfma_f32_16x16x32_bf16((a), (b), (c), 0, 0, 0)

__device__ __forceinline__ unsigned short bf_hi(float x) {
    unsigned u = __float_as_uint(x);
    return (unsigned short)((u + 0x7fffu + ((u >> 16) & 1u)) >> 16);
}
__device__ __forceinline__ void bf_split(float x, unsigned short& h, unsigned short& l) {
    unsigned u  = __float_as_uint(x);
    unsigned hu = (u + 0x7fffu + ((u >> 16) & 1u)) >> 16;
    h = (unsigned short)hu;
    l = bf_hi(x - __uint_as_float(hu << 16));
}

// ---------------------------------------------------------------------------
// wprep: W[512k][512n] fp32 -> Wt hi/lo bf16 in [n][k] layout (B-frag layout).
// ---------------------------------------------------------------------------
__global__ __launch_bounds__(256)
void wprep(const float* __restrict__ WQ, const float* __restrict__ WK,
           const float* __restrict__ WV, unsigned short* __restrict__ wt)
{
    __shared__ float T[64][68];
    const int z = blockIdx.z;
    const float* W = (z == 0) ? WQ : (z == 1) ? WK : WV;
    unsigned short* Wth = wt + (size_t)z * 524288;
    unsigned short* Wtl = Wth + 262144;
    const int k0 = blockIdx.x * 64, n0 = blockIdx.y * 64;
    const int t = threadIdx.x;
    #pragma unroll
    for (int e = 0; e < 4; ++e) {
        int f = e * 256 + t, r = f >> 4, c4 = (f & 15) << 2;
        *(float4*)&T[r][c4] = *(const float4*)&W[(size_t)(k0 + r) * 512 + n0 + c4];
    }
    __syncthreads();
    #pragma unroll
    for (int e = 0; e < 4; ++e) {
        int f = e * 256 + t, nr = f >> 4, kc4 = (f & 15) << 2;
        ushort4 h, l;
        bf_split(T[kc4 + 0][nr], h.x, l.x);
        bf_split(T[kc4 + 1][nr], h.y, l.y);
        bf_split(T[kc4 + 2][nr], h.z, l.z);
        bf_split(T[kc4 + 3][nr], h.w, l.w);
        *(ushort4*)&Wth[(size_t)(n0 + nr) * 512 + k0 + kc4] = h;
        *(ushort4*)&Wtl[(size_t)(n0 + nr) * 512 + k0 + kc4] = l;
    }
}

// ---------------------------------------------------------------------------
// proj_mfma: C = X@W via split-bf16 3-pass MFMA. 128x128 tile, BK=32,
// 4 waves, wave tile 64x64 (4x4 of 16x16x32). Outputs [B,H,L,D]:
// q (x0.125) and k as hi+lo pairs, v as hi only.
// ---------------------------------------------------------------------------
#define PSTR 40   // LDS row stride in ushorts (32 data + 8 pad -> uniform banks)

__global__ __launch_bounds__(256)
void proj_mfma(const float* __restrict__ Qin, const float* __restrict__ Kin,
               const float* __restrict__ Vin, const unsigned short* __restrict__ wt,
               unsigned short* __restrict__ qh, unsigned short* __restrict__ ql,
               unsigned short* __restrict__ kh, unsigned short* __restrict__ kl,
               unsigned short* __restrict__ vh)
{
    __shared__ unsigned short Ah[128 * PSTR], Al[128 * PSTR],
                              Bh[128 * PSTR], Bl[128 * PSTR];
    const int z = blockIdx.z;
    const float* X = (z == 0) ? Qin : (z == 1) ? Kin : Vin;
    unsigned short* oh = (z == 0) ? qh : (z == 1) ? kh : vh;
    unsigned short* ol = (z == 0) ? ql : kl;           // unused when z==2
    const unsigned short* Wth = wt + (size_t)z * 524288;
    const unsigned short* Wtl = Wth + 262144;

    const int t = threadIdx.x, lane = t & 63, w = t >> 6;
    const int wm = w & 1, wn = w >> 1;
    const int m0 = blockIdx.x * 128, n0 = blockIdx.y * 128;
    const int lm = lane & 15, lq = lane >> 4;
    const int ar = t >> 1, ak = (t & 1) * 16;

    const float* Xp = X + (size_t)(m0 + ar) * 512 + ak;
    const unsigned short* Bph = Wth + (size_t)(n0 + ar) * 512 + ak;
    const unsigned short* Bpl = Wtl + (size_t)(n0 + ar) * 512 + ak;

    f32x4 acc[4][4];
    #pragma unroll
    for (int i = 0; i < 4; ++i)
        #pragma unroll
        for (int j = 0; j < 4; ++j) acc[i][j] = 0.f;

    for (int k0 = 0; k0 < 512; k0 += 32) {
        float4 av[4];
        #pragma unroll
        for (int e = 0; e < 4; ++e) av[e] = *(const float4*)(Xp + k0 + e * 4);
        uint4 b0 = *(const uint4*)(Bph + k0);
        uint4 b1 = *(const uint4*)(Bph + k0 + 8);
        uint4 b2 = *(const uint4*)(Bpl + k0);
        uint4 b3 = *(const uint4*)(Bpl + k0 + 8);
        __syncthreads();
        #pragma unroll
        for (int e = 0; e < 4; ++e) {
            ushort4 h, l;
            bf_split(av[e].x, h.x, l.x);
            bf_split(av[e].y, h.y, l.y);
            bf_split(av[e].z, h.z, l.z);
            bf_split(av[e].w, h.w, l.w);
            *(ushort4*)&Ah[ar * PSTR + ak + e * 4] = h;
            *(ushort4*)&Al[ar * PSTR + ak + e * 4] = l;
        }
        *(uint4*)&Bh[ar * PSTR + ak]     = b0;
        *(uint4*)&Bh[ar * PSTR + ak + 8] = b1;
        *(uint4*)&Bl[ar * PSTR + ak]     = b2;
        *(uint4*)&Bl[ar * PSTR + ak + 8] = b3;
        __syncthreads();

        short8 a_h[4], a_l[4];
        #pragma unroll
        for (int mi = 0; mi < 4; ++mi) {
            int off = (wm * 64 + mi * 16 + lm) * PSTR + lq * 8;
            a_h[mi] = *(const short8*)&Ah[off];
            a_l[mi] = *(const short8*)&Al[off];
        }
        #pragma unroll
        for (int ni = 0; ni < 4; ++ni) {
            int off = (wn * 64 + ni * 16 + lm) * PSTR + lq * 8;
            short8 b_h = *(const short8*)&Bh[off];
            short8 b_l = *(const short8*)&Bl[off];
            #pragma unroll
            for (int mi = 0; mi < 4; ++mi) {
                acc[mi][ni] = MFMA16(a_l[mi], b_h, acc[mi][ni]);
                acc[mi][ni] = MFMA16(a_h[mi], b_l, acc[mi][ni]);
                acc[mi][ni] = MFMA16(a_h[mi], b_h, acc[mi][ni]);
            }
        }
    }

    const float sc = (z == 0) ? 0.125f : 1.0f;   // fold 1/sqrt(64) into q
    #pragma unroll
    for (int mi = 0; mi < 4; ++mi)
        #pragma unroll
        for (int ni = 0; ni < 4; ++ni) {
            int n_abs = n0 + wn * 64 + ni * 16 + lm;
            int hd = n_abs >> 6, d = n_abs & 63;
            #pragma unroll
            for (int r = 0; r < 4; ++r) {
                int m_abs = m0 + wm * 64 + mi * 16 + lq * 4 + r;
                int b = m_abs >> 10, li = m_abs & 1023;
                size_t idx = (((size_t)b * NHEAD + hd) * LEN + li) * HDIM + d;
                unsigned short hv, lv;
                bf_split(acc[mi][ni][r] * sc, hv, lv);
                oh[idx] = hv;
                if (z < 2) ol[idx] = lv;
            }
        }
}

// ---------------------------------------------------------------------------
// attn_mfma: causal flash attention, MFMA. Block = 128 q rows (4 waves x 32),
// 64 keys/iter. Q frags pinned in registers (split), K split in LDS,
// V hi-only transposed in LDS, P round-trips LDS as bf16.
// ---------------------------------------------------------------------------
__global__ __launch_bounds__(256)
void attn_mfma(const unsigned short* __restrict__ qh, const unsigned short* __restrict__ ql,
               const unsigned short* __restrict__ kh, const unsigned short* __restrict__ kl,
               const unsigned short* __restrict__ vh, float* __restrict__ out)
{
    __shared__ unsigned short sm[23040];          // 46080 B
    unsigned short* Kh  = sm;                     // 64*72
    unsigned short* Kl  = sm + 4608;              // 64*72
    unsigned short* Vt  = sm + 9216;              // 64*72  [d][key]
    unsigned short* Pb  = sm + 13824;             // 128*72 [q][key]
    unsigned short* Qsh = sm;                     // overlay (staging only)
    unsigned short* Qsl = sm + 9216;              // overlay (staging only)

    const int t = threadIdx.x, lane = t & 63, w = t >> 6;
    const int lm = lane & 15, lq = lane >> 4;
    const int qt = (int)gridDim.x - 1 - (int)blockIdx.x;   // heavy tiles first
    const int bh = blockIdx.y;
    const size_t base = (size_t)bh * LEN * HDIM;
    const unsigned short* qhb = qh + base;
    const unsigned short* qlb = ql + base;
    const unsigned short* khb = kh + base;
    const unsigned short* klb = kl + base;
    const unsigned short* vhb = vh + base;
    const int Q0  = qt * 128;
    const int Q0w = Q0 + w * 32;

    // ---- stage Q (pre-scaled in proj), pull frags to registers ----
    #pragma unroll
    for (int e = 0; e < 4; ++e) {
        int f = e * 256 + t, r = f >> 3, s8 = (f & 7) * 8;
        *(uint4*)&Qsh[r * 72 + s8] = *(const uint4*)&qhb[(size_t)(Q0 + r) * 64 + s8];
        *(uint4*)&Qsl[r * 72 + s8] = *(const uint4*)&qlb[(size_t)(Q0 + r) * 64 + s8];
    }
    __syncthreads();
    short8 qfh[2][2], qfl[2][2];
    #pragma unroll
    for (int mi = 0; mi < 2; ++mi)
        #pragma unroll
        for (int ks = 0; ks < 2; ++ks) {
            int off = (w * 32 + mi * 16 + lm) * 72 + ks * 32 + lq * 8;
            qfh[mi][ks] = *(const short8*)&Qsh[off];
            qfl[mi][ks] = *(const short8*)&Qsl[off];
        }

    float m_i[2][4], l_i[2][4];
    f32x4 oacc[2][4];
    #pragma unroll
    for (int mi = 0; mi < 2; ++mi)
        #pragma unroll
        for (int r = 0; r < 4; ++r) { m_i[mi][r] = -1e30f; l_i[mi][r] = 0.f; }
    #pragma unroll
    for (int mi = 0; mi < 2; ++mi)
        #pragma unroll
        for (int nd = 0; nd < 4; ++nd) oacc[mi][nd] = 0.f;

    const int jend = 2 * qt + 1;
    for (int jb = 0; jb <= jend; ++jb) {
        __syncthreads();   // prior frag reads done (also covers Q-frag reads at jb=0)
        // stage K hi/lo (straight copies, already split)
        #pragma unroll
        for (int e = 0; e < 2; ++e) {
            int f = e * 256 + t, r = f >> 3, s8 = (f & 7) * 8;
            *(uint4*)&Kh[r * 72 + s8] = *(const uint4*)&khb[(size_t)(jb * 64 + r) * 64 + s8];
            *(uint4*)&Kl[r * 72 + s8] = *(const uint4*)&klb[(size_t)(jb * 64 + r) * 64 + s8];
        }
        // stage V transposed: key-on-lane scatter (bank-uniform)
        {
            int key = t & 63, g0 = t >> 6;
            #pragma unroll
            for (int e = 0; e < 4; ++e) {
                int g = g0 + e * 4;
                ushort4 vv = *(const ushort4*)&vhb[(size_t)(jb * 64 + key) * 64 + g * 4];
                Vt[(g * 4 + 0) * 72 + key] = vv.x;
                Vt[(g * 4 + 1) * 72 + key] = vv.y;
                Vt[(g * 4 + 2) * 72 + key] = vv.z;
                Vt[(g * 4 + 3) * 72 + key] = vv.w;
            }
        }
        __syncthreads();

        const bool active = (jb * 64 <= Q0w + 31);
        if (active) {
            f32x4 sf[2][4];
            #pragma unroll
            for (int mi = 0; mi < 2; ++mi)
                #pragma unroll
                for (int ni = 0; ni < 4; ++ni) sf[mi][ni] = 0.f;
            #pragma unroll
            for (int ks = 0; ks < 2; ++ks)
                #pragma unroll
                for (int ni = 0; ni < 4; ++ni) {
                    int off = (ni * 16 + lm) * 72 + ks * 32 + lq * 8;
                    short8 b_h = *(const short8*)&Kh[off];
                    short8 b_l = *(const short8*)&Kl[off];
                    #pragma unroll
                    for (int mi = 0; mi < 2; ++mi) {
                        sf[mi][ni] = MFMA16(qfl[mi][ks], b_h, sf[mi][ni]);
                        sf[mi][ni] = MFMA16(qfh[mi][ks], b_l, sf[mi][ni]);
                        sf[mi][ni] = MFMA16(qfh[mi][ks], b_h, sf[mi][ni]);
                    }
                }
            if (jb * 64 + 63 > Q0w) {   // causal mask (diagonal vicinity only)
                #pragma unroll
                for (int mi = 0; mi < 2; ++mi)
                    #pragma unroll
                    for (int ni = 0; ni < 4; ++ni) {
                        int key = jb * 64 + ni * 16 + lm;
                        #pragma unroll
                        for (int r = 0; r < 4; ++r) {
                            int qi = Q0w + mi * 16 + lq * 4 + r;
                            if (key > qi) sf[mi][ni][r] = -1e30f;
                        }
                    }
            }
            // online softmax; rows live on 16-lane quads -> DPP shuffles
            #pragma unroll
            for (int mi = 0; mi < 2; ++mi)
                #pragma unroll
                for (int r = 0; r < 4; ++r) {
                    float mv = fmaxf(fmaxf(sf[mi][0][r], sf[mi][1][r]),
                                     fmaxf(sf[mi][2][r], sf[mi][3][r]));
                    mv = fmaxf(mv, __shfl_xor(mv, 1));
                    mv = fmaxf(mv, __shfl_xor(mv, 2));
                    mv = fmaxf(mv, __shfl_xor(mv, 4));
                    mv = fmaxf(mv, __shfl_xor(mv, 8));
                    float mo = m_i[mi][r];
                    float mn = fmaxf(mo, mv);
                    float al = __expf(mo - mn);
                    m_i[mi][r] = mn;
                    float rs = 0.f;
                    int prow = (w * 32 + mi * 16 + lq * 4 + r) * 72 + lm;
                    #pragma unroll
                    for (int ni = 0; ni < 4; ++ni) {
                        float p = __expf(sf[mi][ni][r] - mn);
                        rs += p;
                        Pb[prow + ni * 16] = bf_hi(p);
                    }
                    rs += __shfl_xor(rs, 1);
                    rs += __shfl_xor(rs, 2);
                    rs += __shfl_xor(rs, 4);
                    rs += __shfl_xor(rs, 8);
                    l_i[mi][r] = l_i[mi][r] * al + rs;
                    #pragma unroll
                    for (int nd = 0; nd < 4; ++nd) oacc[mi][nd][r] *= al;
                }
        }
        __syncthreads();   // P visible (kept for safety; uniform for all waves)
        if (active) {
            short8 pf[2][2];
            #pragma unroll
            for (int mi = 0; mi < 2; ++mi)
                #pragma unroll
                for (int ks = 0; ks < 2; ++ks)
                    pf[mi][ks] = *(const short8*)&Pb[(w * 32 + mi * 16 + lm) * 72 + ks * 32 + lq * 8];
            #pragma unroll
            for (int ks = 0; ks < 2; ++ks)
                #pragma unroll
                for (int nd = 0; nd < 4; ++nd) {
                    short8 vf = *(const short8*)&Vt[(nd * 16 + lm) * 72 + ks * 32 + lq * 8];
                    #pragma unroll
                    for (int mi = 0; mi < 2; ++mi)
                        oacc[mi][nd] = MFMA16(pf[mi][ks], vf, oacc[mi][nd]);
                }
        }
    }

    // epilogue: divide by l, write [B, L, H*D] fp32
    const int b = bh >> 3, hd = bh & 7;
    #pragma unroll
    for (int mi = 0; mi < 2; ++mi)
        #pragma unroll
        for (int r = 0; r < 4; ++r) {
            int qrow = Q0w + mi * 16 + lq * 4 + r;
            float inv = 1.0f / l_i[mi][r];
            #pragma unroll
            for (int nd = 0; nd < 4; ++nd) {
                int d = nd * 16 + lm;
                out[((size_t)b * LEN + qrow) * (NHEAD * HDIM) + hd * 64 + d] =
                    oacc[mi][nd][r] * inv;
            }
        }
}

// ---------------------------------------------------------------------------
extern "C" void kernel_launch(void* const* d_in, const int* in_sizes, int n_in,
                              void* d_out, int out_size, void* d_ws, size_t ws_size,
                              hipStream_t stream)
{
    const float* Qin = (const float*)d_in[0];
    const float* Kin = (const float*)d_in[1];
    const float* Vin = (const float*)d_in[2];
    const float* WQ  = (const float*)d_in[3];
    const float* WK  = (const float*)d_in[4];
    const float* WV  = (const float*)d_in[5];

    unsigned short* ws = (unsigned short*)d_ws;
    const size_t per = (size_t)BATCH * NHEAD * LEN * HDIM;   // 4,194,304 elements
    unsigned short* qh = ws;
    unsigned short* ql = ws + per;
    unsigned short* kh = ws + 2 * per;
    unsigned short* kl = ws + 3 * per;
    unsigned short* vh = ws + 4 * per;
    unsigned short* wt = ws + 5 * per;                       // 3*2*512*512 = 1.5M elems
    // total ws use: 5*8 MB + 3 MB = 43 MB

    wprep    <<<dim3(8, 8, 3),  256, 0, stream>>>(WQ, WK, WV, wt);
    proj_mfma<<<dim3(64, 4, 3), 256, 0, stream>>>(Qin, Kin, Vin, wt, qh, ql, kh, kl, vh);
    attn_mfma<<<dim3(8, 64),    256, 0, stream>>>(qh, ql, kh, kl, vh, (float*)d_out);
}

// Round 3
// 202.071 us; speedup vs baseline: 3.3113x; 1.1175x over previous
//
#include <hip/hip_runtime.h>
#include <cstddef>

#define LEN    1024
#define DIN    512
#define NHEAD  8
#define HDIM   64
#define BATCH  8

typedef __attribute__((ext_vector_type(8))) short  short8;
typedef __attribute__((ext_vector_type(4))) float  f32x4;

#define MFMA16(a, b, c) __builtin_amdgcn_mfma_f32_16x16x32_bf16((a), (b), (c), 0, 0, 0)

__device__ __forceinline__ unsigned short bf_hi(float x) {
    unsigned u = __float_as_uint(x);
    return (unsigned short)((u + 0x7fffu + ((u >> 16) & 1u)) >> 16);
}
__device__ __forceinline__ void bf_split(float x, unsigned short& h, unsigned short& l) {
    unsigned u  = __float_as_uint(x);
    unsigned hu = (u + 0x7fffu + ((u >> 16) & 1u)) >> 16;
    h = (unsigned short)hu;
    l = bf_hi(x - __uint_as_float(hu << 16));
}
__device__ __forceinline__ void unpack4(uint4 u, ushort4& h, ushort4& l) {
    h = make_ushort4((unsigned short)(u.x >> 16), (unsigned short)(u.y >> 16),
                     (unsigned short)(u.z >> 16), (unsigned short)(u.w >> 16));
    l = make_ushort4((unsigned short)(u.x & 0xffff), (unsigned short)(u.y & 0xffff),
                     (unsigned short)(u.z & 0xffff), (unsigned short)(u.w & 0xffff));
}

// DPP cross-lane (16-lane row) reductions — full-rate VALU, no LDS.
template<int CTRL>
__device__ __forceinline__ float dpp_mov(float x) {
    return __int_as_float(__builtin_amdgcn_update_dpp(
        0, __float_as_int(x), CTRL, 0xF, 0xF, true));
}
__device__ __forceinline__ float red16_max(float x) {
    x = fmaxf(x, dpp_mov<0xB1>(x));    // quad_perm xor1
    x = fmaxf(x, dpp_mov<0x4E>(x));    // quad_perm xor2
    x = fmaxf(x, dpp_mov<0x141>(x));   // row_half_mirror
    x = fmaxf(x, dpp_mov<0x140>(x));   // row_mirror
    return x;
}
__device__ __forceinline__ float red16_sum(float x) {
    x += dpp_mov<0xB1>(x);
    x += dpp_mov<0x4E>(x);
    x += dpp_mov<0x141>(x);
    x += dpp_mov<0x140>(x);
    return x;
}

// ---------------------------------------------------------------------------
// wprep: W[512k][512n] fp32 -> Wt hi/lo bf16 in [n][k] layout (B-frag layout).
// ---------------------------------------------------------------------------
__global__ __launch_bounds__(256)
void wprep(const float* __restrict__ WQ, const float* __restrict__ WK,
           const float* __restrict__ WV, unsigned short* __restrict__ wt)
{
    __shared__ float T[64][68];
    const int z = blockIdx.z;
    const float* W = (z == 0) ? WQ : (z == 1) ? WK : WV;
    unsigned short* Wth = wt + (size_t)z * 524288;
    unsigned short* Wtl = Wth + 262144;
    const int k0 = blockIdx.x * 64, n0 = blockIdx.y * 64;
    const int t = threadIdx.x;
    #pragma unroll
    for (int e = 0; e < 4; ++e) {
        int f = e * 256 + t, r = f >> 4, c4 = (f & 15) << 2;
        *(float4*)&T[r][c4] = *(const float4*)&W[(size_t)(k0 + r) * 512 + n0 + c4];
    }
    __syncthreads();
    #pragma unroll
    for (int e = 0; e < 4; ++e) {
        int f = e * 256 + t, nr = f >> 4, kc4 = (f & 15) << 2;
        ushort4 h, l;
        bf_split(T[kc4 + 0][nr], h.x, l.x);
        bf_split(T[kc4 + 1][nr], h.y, l.y);
        bf_split(T[kc4 + 2][nr], h.z, l.z);
        bf_split(T[kc4 + 3][nr], h.w, l.w);
        *(ushort4*)&Wth[(size_t)(n0 + nr) * 512 + k0 + kc4] = h;
        *(ushort4*)&Wtl[(size_t)(n0 + nr) * 512 + k0 + kc4] = l;
    }
}

// ---------------------------------------------------------------------------
// proj_mfma: C = X@W via split-bf16 3-pass MFMA. 128x128 tile, BK=32.
// Outputs: q,k as packed (hi<<16|lo) uint in [B,H,L,D];
//          v as hi-only ushort in [B,H,D,L] (transposed).
// q pre-scaled by 0.125*log2(e) so attention softmax runs in base 2.
// ---------------------------------------------------------------------------
#define PSTR 40   // LDS row stride in ushorts

__global__ __launch_bounds__(256)
void proj_mfma(const float* __restrict__ Qin, const float* __restrict__ Kin,
               const float* __restrict__ Vin, const unsigned short* __restrict__ wt,
               unsigned int* __restrict__ qhl, unsigned int* __restrict__ khl,
               unsigned short* __restrict__ vh)
{
    __shared__ unsigned short Ah[128 * PSTR], Al[128 * PSTR],
                              Bh[128 * PSTR], Bl[128 * PSTR];
    const int z = blockIdx.z;
    const float* X = (z == 0) ? Qin : (z == 1) ? Kin : Vin;
    const unsigned short* Wth = wt + (size_t)z * 524288;
    const unsigned short* Wtl = Wth + 262144;

    const int t = threadIdx.x, lane = t & 63, w = t >> 6;
    const int wm = w & 1, wn = w >> 1;
    const int m0 = blockIdx.x * 128, n0 = blockIdx.y * 128;
    const int lm = lane & 15, lq = lane >> 4;
    const int ar = t >> 1, ak = (t & 1) * 16;

    const float* Xp = X + (size_t)(m0 + ar) * 512 + ak;
    const unsigned short* Bph = Wth + (size_t)(n0 + ar) * 512 + ak;
    const unsigned short* Bpl = Wtl + (size_t)(n0 + ar) * 512 + ak;

    f32x4 acc[4][4];
    #pragma unroll
    for (int i = 0; i < 4; ++i)
        #pragma unroll
        for (int j = 0; j < 4; ++j) acc[i][j] = 0.f;

    // prefetch k0 = 0
    float4 av[4];
    uint4 b0, b1, b2, b3;
    #pragma unroll
    for (int e = 0; e < 4; ++e) av[e] = *(const float4*)(Xp + e * 4);
    b0 = *(const uint4*)(Bph);
    b1 = *(const uint4*)(Bph + 8);
    b2 = *(const uint4*)(Bpl);
    b3 = *(const uint4*)(Bpl + 8);

    for (int k0 = 0; k0 < 512; k0 += 32) {
        __syncthreads();                       // prev iter's frag reads done
        #pragma unroll
        for (int e = 0; e < 4; ++e) {
            ushort4 h, l;
            bf_split(av[e].x, h.x, l.x);
            bf_split(av[e].y, h.y, l.y);
            bf_split(av[e].z, h.z, l.z);
            bf_split(av[e].w, h.w, l.w);
            *(ushort4*)&Ah[ar * PSTR + ak + e * 4] = h;
            *(ushort4*)&Al[ar * PSTR + ak + e * 4] = l;
        }
        *(uint4*)&Bh[ar * PSTR + ak]     = b0;
        *(uint4*)&Bh[ar * PSTR + ak + 8] = b1;
        *(uint4*)&Bl[ar * PSTR + ak]     = b2;
        *(uint4*)&Bl[ar * PSTR + ak + 8] = b3;
        __syncthreads();

        if (k0 + 32 < 512) {                   // prefetch next (overlaps MFMA)
            #pragma unroll
            for (int e = 0; e < 4; ++e) av[e] = *(const float4*)(Xp + k0 + 32 + e * 4);
            b0 = *(const uint4*)(Bph + k0 + 32);
            b1 = *(const uint4*)(Bph + k0 + 40);
            b2 = *(const uint4*)(Bpl + k0 + 32);
            b3 = *(const uint4*)(Bpl + k0 + 40);
        }

        short8 a_h[4], a_l[4];
        #pragma unroll
        for (int mi = 0; mi < 4; ++mi) {
            int off = (wm * 64 + mi * 16 + lm) * PSTR + lq * 8;
            a_h[mi] = *(const short8*)&Ah[off];
            a_l[mi] = *(const short8*)&Al[off];
        }
        #pragma unroll
        for (int ni = 0; ni < 4; ++ni) {
            int off = (wn * 64 + ni * 16 + lm) * PSTR + lq * 8;
            short8 b_h = *(const short8*)&Bh[off];
            short8 b_l = *(const short8*)&Bl[off];
            #pragma unroll
            for (int mi = 0; mi < 4; ++mi) {
                acc[mi][ni] = MFMA16(a_l[mi], b_h, acc[mi][ni]);
                acc[mi][ni] = MFMA16(a_h[mi], b_l, acc[mi][ni]);
                acc[mi][ni] = MFMA16(a_h[mi], b_h, acc[mi][ni]);
            }
        }
    }

    if (z < 2) {
        unsigned int* o = (z == 0) ? qhl : khl;
        const float sc = (z == 0) ? 0.18033688011112042f : 1.0f;  // 0.125*log2(e)
        #pragma unroll
        for (int mi = 0; mi < 4; ++mi)
            #pragma unroll
            for (int ni = 0; ni < 4; ++ni) {
                int n_abs = n0 + wn * 64 + ni * 16 + lm;
                int hd = n_abs >> 6, d = n_abs & 63;
                #pragma unroll
                for (int r = 0; r < 4; ++r) {
                    int m_abs = m0 + wm * 64 + mi * 16 + lq * 4 + r;
                    int b = m_abs >> 10, li = m_abs & 1023;
                    unsigned short hv, lv;
                    bf_split(acc[mi][ni][r] * sc, hv, lv);
                    o[(((size_t)b * NHEAD + hd) * LEN + li) * HDIM + d] =
                        ((unsigned)hv << 16) | lv;
                }
            }
    } else {
        // v: [B,H,D,L], hi only, vector stores over 4 consecutive l
        #pragma unroll
        for (int mi = 0; mi < 4; ++mi) {
            int m_base = m0 + wm * 64 + mi * 16 + lq * 4;
            int b = m_base >> 10, l0 = m_base & 1023;
            #pragma unroll
            for (int ni = 0; ni < 4; ++ni) {
                int n_abs = n0 + wn * 64 + ni * 16 + lm;
                int hd = n_abs >> 6, d = n_abs & 63;
                ushort4 hv = make_ushort4(bf_hi(acc[mi][ni][0]), bf_hi(acc[mi][ni][1]),
                                          bf_hi(acc[mi][ni][2]), bf_hi(acc[mi][ni][3]));
                *(ushort4*)&vh[(((size_t)b * NHEAD + hd) * HDIM + d) * LEN + l0] = hv;
            }
        }
    }
}

// ---------------------------------------------------------------------------
// attn_mfma: causal flash attention. Block = 128 q rows (4 waves x 32).
// K packed uint [B,H,L,D] -> unpack to Kh/Kl LDS; V [B,H,D,L] -> straight
// b128 copy to Vt. Register prefetch of next K/V tile overlaps compute.
// Softmax (base 2) uses DPP 16-lane reductions.
// ---------------------------------------------------------------------------
__global__ __launch_bounds__(256)
void attn_mfma(const unsigned int* __restrict__ qhl, const unsigned int* __restrict__ khl,
               const unsigned short* __restrict__ vth, float* __restrict__ out)
{
    __shared__ unsigned short sm[23040];          // 46080 B
    unsigned short* Kh  = sm;                     // 64*72
    unsigned short* Kl  = sm + 4608;
    unsigned short* Vt  = sm + 9216;              // [d][key]
    unsigned short* Pb  = sm + 13824;             // 128*72 [q][key]
    unsigned short* Qsh = sm;                     // overlay (staging only)
    unsigned short* Qsl = sm + 9216;

    const int t = threadIdx.x, lane = t & 63, w = t >> 6;
    const int lm = lane & 15, lq = lane >> 4;
    const int bx = blockIdx.x;
    const int qt = 7 - (bx >> 6);                 // heavy tiles dispatch first
    const int bh = bx & 63;
    const size_t base = (size_t)bh * LEN * HDIM;
    const unsigned int*   qb = qhl + base;
    const unsigned int*   kb = khl + base;
    const unsigned short* vb = vth + base;        // [d][l]
    const int Q0  = qt * 128;
    const int Q0w = Q0 + w * 32;

    // ---- stage Q (packed), pull split frags to registers ----
    #pragma unroll
    for (int e = 0; e < 8; ++e) {
        int f = e * 256 + t, r = f >> 4, c4 = (f & 15) << 2;
        uint4 u = *(const uint4*)&qb[(size_t)(Q0 + r) * 64 + c4];
        ushort4 h, l;
        unpack4(u, h, l);
        *(ushort4*)&Qsh[r * 72 + c4] = h;
        *(ushort4*)&Qsl[r * 72 + c4] = l;
    }
    __syncthreads();
    short8 qfh[2][2], qfl[2][2];
    #pragma unroll
    for (int mi = 0; mi < 2; ++mi)
        #pragma unroll
        for (int ks = 0; ks < 2; ++ks) {
            int off = (w * 32 + mi * 16 + lm) * 72 + ks * 32 + lq * 8;
            qfh[mi][ks] = *(const short8*)&Qsh[off];
            qfl[mi][ks] = *(const short8*)&Qsl[off];
        }

    float m_i[2][4], l_i[2][4];
    f32x4 oacc[2][4];
    #pragma unroll
    for (int mi = 0; mi < 2; ++mi)
        #pragma unroll
        for (int r = 0; r < 4; ++r) { m_i[mi][r] = -1e30f; l_i[mi][r] = 0.f; }
    #pragma unroll
    for (int mi = 0; mi < 2; ++mi)
        #pragma unroll
        for (int nd = 0; nd < 4; ++nd) oacc[mi][nd] = 0.f;

    // staging-index precompute
    const int kr_ = t >> 4, kc4 = (t & 15) << 2;          // K: rows kr_+64e/... per e
    const int vd_ = t >> 3, vs8 = (t & 7) << 3;           // V: d rows, key chunks

    // prefetch jb = 0
    uint4 kreg[4], vreg[2];
    #pragma unroll
    for (int e = 0; e < 4; ++e)
        kreg[e] = *(const uint4*)&kb[(size_t)(e * 16 + kr_) * 64 + kc4];
    #pragma unroll
    for (int e = 0; e < 2; ++e)
        vreg[e] = *(const uint4*)&vb[(size_t)(e * 32 + vd_) * LEN + vs8];

    const int jend = 2 * qt + 1;
    for (int jb = 0; jb <= jend; ++jb) {
        __syncthreads();   // prior frag reads done (covers Q-frag reads at jb=0)
        #pragma unroll
        for (int e = 0; e < 4; ++e) {
            int r = e * 16 + kr_;
            ushort4 h, l;
            unpack4(kreg[e], h, l);
            *(ushort4*)&Kh[r * 72 + kc4] = h;
            *(ushort4*)&Kl[r * 72 + kc4] = l;
        }
        #pragma unroll
        for (int e = 0; e < 2; ++e)
            *(uint4*)&Vt[(e * 32 + vd_) * 72 + vs8] = vreg[e];
        __syncthreads();

        if (jb < jend) {   // prefetch next tile; overlaps all compute below
            #pragma unroll
            for (int e = 0; e < 4; ++e)
                kreg[e] = *(const uint4*)&kb[(size_t)((jb + 1) * 64 + e * 16 + kr_) * 64 + kc4];
            #pragma unroll
            for (int e = 0; e < 2; ++e)
                vreg[e] = *(const uint4*)&vb[(size_t)(e * 32 + vd_) * LEN + (jb + 1) * 64 + vs8];
        }

        const bool active = (jb * 64 <= Q0w + 31);
        if (active) {
            f32x4 sf[2][4];
            #pragma unroll
            for (int mi = 0; mi < 2; ++mi)
                #pragma unroll
                for (int ni = 0; ni < 4; ++ni) sf[mi][ni] = 0.f;
            #pragma unroll
            for (int ks = 0; ks < 2; ++ks)
                #pragma unroll
                for (int ni = 0; ni < 4; ++ni) {
                    int off = (ni * 16 + lm) * 72 + ks * 32 + lq * 8;
                    short8 b_h = *(const short8*)&Kh[off];
                    short8 b_l = *(const short8*)&Kl[off];
                    #pragma unroll
                    for (int mi = 0; mi < 2; ++mi) {
                        sf[mi][ni] = MFMA16(qfl[mi][ks], b_h, sf[mi][ni]);
                        sf[mi][ni] = MFMA16(qfh[mi][ks], b_l, sf[mi][ni]);
                        sf[mi][ni] = MFMA16(qfh[mi][ks], b_h, sf[mi][ni]);
                    }
                }
            if (jb * 64 + 63 > Q0w) {   // causal mask near diagonal
                #pragma unroll
                for (int mi = 0; mi < 2; ++mi)
                    #pragma unroll
                    for (int ni = 0; ni < 4; ++ni) {
                        int key = jb * 64 + ni * 16 + lm;
                        #pragma unroll
                        for (int r = 0; r < 4; ++r) {
                            int qi = Q0w + mi * 16 + lq * 4 + r;
                            if (key > qi) sf[mi][ni][r] = -1e30f;
                        }
                    }
            }
            // online softmax (base 2); rows on 16-lane groups -> DPP reduce
            #pragma unroll
            for (int mi = 0; mi < 2; ++mi)
                #pragma unroll
                for (int r = 0; r < 4; ++r) {
                    float mv = fmaxf(fmaxf(sf[mi][0][r], sf[mi][1][r]),
                                     fmaxf(sf[mi][2][r], sf[mi][3][r]));
                    mv = red16_max(mv);
                    float mo = m_i[mi][r];
                    float mn = fmaxf(mo, mv);
                    float al = __builtin_amdgcn_exp2f(mo - mn);
                    m_i[mi][r] = mn;
                    float rs = 0.f;
                    int prow = (w * 32 + mi * 16 + lq * 4 + r) * 72 + lm;
                    #pragma unroll
                    for (int ni = 0; ni < 4; ++ni) {
                        float p = __builtin_amdgcn_exp2f(sf[mi][ni][r] - mn);
                        rs += p;
                        Pb[prow + ni * 16] = bf_hi(p);
                    }
                    rs = red16_sum(rs);
                    l_i[mi][r] = l_i[mi][r] * al + rs;
                    #pragma unroll
                    for (int nd = 0; nd < 4; ++nd) oacc[mi][nd][r] *= al;
                }
            // P round-trip is same-wave rows; lgkmcnt ordering suffices (no barrier)
            short8 pf[2][2];
            #pragma unroll
            for (int mi = 0; mi < 2; ++mi)
                #pragma unroll
                for (int ks = 0; ks < 2; ++ks)
                    pf[mi][ks] = *(const short8*)&Pb[(w * 32 + mi * 16 + lm) * 72 + ks * 32 + lq * 8];
            #pragma unroll
            for (int ks = 0; ks < 2; ++ks)
                #pragma unroll
                for (int nd = 0; nd < 4; ++nd) {
                    short8 vf = *(const short8*)&Vt[(nd * 16 + lm) * 72 + ks * 32 + lq * 8];
                    #pragma unroll
                    for (int mi = 0; mi < 2; ++mi)
                        oacc[mi][nd] = MFMA16(pf[mi][ks], vf, oacc[mi][nd]);
                }
        }
    }

    // epilogue: divide by l, write [B, L, H*D] fp32
    const int b = bh >> 3, hd = bh & 7;
    #pragma unroll
    for (int mi = 0; mi < 2; ++mi)
        #pragma unroll
        for (int r = 0; r < 4; ++r) {
            int qrow = Q0w + mi * 16 + lq * 4 + r;
            float inv = 1.0f / l_i[mi][r];
            #pragma unroll
            for (int nd = 0; nd < 4; ++nd) {
                int d = nd * 16 + lm;
                out[((size_t)b * LEN + qrow) * (NHEAD * HDIM) + hd * 64 + d] =
                    oacc[mi][nd][r] * inv;
            }
        }
}

// ---------------------------------------------------------------------------
extern "C" void kernel_launch(void* const* d_in, const int* in_sizes, int n_in,
                              void* d_out, int out_size, void* d_ws, size_t ws_size,
                              hipStream_t stream)
{
    const float* Qin = (const float*)d_in[0];
    const float* Kin = (const float*)d_in[1];
    const float* Vin = (const float*)d_in[2];
    const float* WQ  = (const float*)d_in[3];
    const float* WK  = (const float*)d_in[4];
    const float* WV  = (const float*)d_in[5];

    const size_t per = (size_t)BATCH * NHEAD * LEN * HDIM;   // 4,194,304 elements
    unsigned int*   qhl = (unsigned int*)d_ws;               // 16 MB
    unsigned int*   khl = qhl + per;                         // 16 MB
    unsigned short* vh  = (unsigned short*)(khl + per);      // 8 MB
    unsigned short* wt  = vh + per;                          // 3 MB   (total 43 MB)

    wprep    <<<dim3(8, 8, 3),  256, 0, stream>>>(WQ, WK, WV, wt);
    proj_mfma<<<dim3(64, 4, 3), 256, 0, stream>>>(Qin, Kin, Vin, wt, qhl, khl, vh);
    attn_mfma<<<dim3(512),      256, 0, stream>>>(qhl, khl, vh, (float*)d_out);
}

// Round 5
// 189.297 us; speedup vs baseline: 3.5348x; 1.0675x over previous
//
#include <hip/hip_runtime.h>
#include <cstddef>

#define LEN    1024
#define DIN    512
#define NHEAD  8
#define HDIM   64
#define BATCH  8

typedef __attribute__((ext_vector_type(8))) short  short8;
typedef __attribute__((ext_vector_type(4))) float  f32x4;

#define MFMA16(a, b, c) __builtin_amdgcn_mfma_f32_16x16x32_bf16((a), (b), (c), 0, 0, 0)
#define PERM_HI 0x07060302u   // result = [a.hi16 : b.hi16]
#define PERM_LO 0x05040100u

__device__ __forceinline__ unsigned short bf_hi(float x) {
    unsigned u = __float_as_uint(x);
    return (unsigned short)((u + 0x7fffu + ((u >> 16) & 1u)) >> 16);
}
__device__ __forceinline__ void bf_split(float x, unsigned short& h, unsigned short& l) {
    unsigned u  = __float_as_uint(x);
    unsigned hu = (u + 0x7fffu + ((u >> 16) & 1u)) >> 16;
    h = (unsigned short)hu;
    l = bf_hi(x - __uint_as_float(hu << 16));
}
__device__ __forceinline__ void unpack4(uint4 u, ushort4& h, ushort4& l) {
    h = make_ushort4((unsigned short)(u.x >> 16), (unsigned short)(u.y >> 16),
                     (unsigned short)(u.z >> 16), (unsigned short)(u.w >> 16));
    l = make_ushort4((unsigned short)(u.x & 0xffff), (unsigned short)(u.y & 0xffff),
                     (unsigned short)(u.z & 0xffff), (unsigned short)(u.w & 0xffff));
}
// 8 packed uints (two uint4) -> 8 hi ushorts + 8 lo ushorts (each one uint4)
__device__ __forceinline__ void unpack8(uint4 a, uint4 b, uint4& h, uint4& l) {
    h = make_uint4(__builtin_amdgcn_perm(a.y, a.x, PERM_HI),
                   __builtin_amdgcn_perm(a.w, a.z, PERM_HI),
                   __builtin_amdgcn_perm(b.y, b.x, PERM_HI),
                   __builtin_amdgcn_perm(b.w, b.z, PERM_HI));
    l = make_uint4(__builtin_amdgcn_perm(a.y, a.x, PERM_LO),
                   __builtin_amdgcn_perm(a.w, a.z, PERM_LO),
                   __builtin_amdgcn_perm(b.y, b.x, PERM_LO),
                   __builtin_amdgcn_perm(b.w, b.z, PERM_LO));
}

// DPP cross-lane (16-lane row) reductions — full-rate VALU, no LDS.
template<int CTRL>
__device__ __forceinline__ float dpp_mov(float x) {
    return __int_as_float(__builtin_amdgcn_update_dpp(
        0, __float_as_int(x), CTRL, 0xF, 0xF, true));
}
__device__ __forceinline__ float red16_max(float x) {
    x = fmaxf(x, dpp_mov<0xB1>(x));
    x = fmaxf(x, dpp_mov<0x4E>(x));
    x = fmaxf(x, dpp_mov<0x141>(x));
    x = fmaxf(x, dpp_mov<0x140>(x));
    return x;
}
__device__ __forceinline__ float red16_sum(float x) {
    x += dpp_mov<0xB1>(x);
    x += dpp_mov<0x4E>(x);
    x += dpp_mov<0x141>(x);
    x += dpp_mov<0x140>(x);
    return x;
}

// ---------------------------------------------------------------------------
// wprep: W[512k][512n] fp32 -> Wt hi/lo bf16 in [n][k] layout (B-frag layout).
// ---------------------------------------------------------------------------
__global__ __launch_bounds__(256)
void wprep(const float* __restrict__ WQ, const float* __restrict__ WK,
           const float* __restrict__ WV, unsigned short* __restrict__ wt)
{
    __shared__ float T[64][68];
    const int z = blockIdx.z;
    const float* W = (z == 0) ? WQ : (z == 1) ? WK : WV;
    unsigned short* Wth = wt + (size_t)z * 524288;
    unsigned short* Wtl = Wth + 262144;
    const int k0 = blockIdx.x * 64, n0 = blockIdx.y * 64;
    const int t = threadIdx.x;
    #pragma unroll
    for (int e = 0; e < 4; ++e) {
        int f = e * 256 + t, r = f >> 4, c4 = (f & 15) << 2;
        *(float4*)&T[r][c4] = *(const float4*)&W[(size_t)(k0 + r) * 512 + n0 + c4];
    }
    __syncthreads();
    #pragma unroll
    for (int e = 0; e < 4; ++e) {
        int f = e * 256 + t, nr = f >> 4, kc4 = (f & 15) << 2;
        ushort4 h, l;
        bf_split(T[kc4 + 0][nr], h.x, l.x);
        bf_split(T[kc4 + 1][nr], h.y, l.y);
        bf_split(T[kc4 + 2][nr], h.z, l.z);
        bf_split(T[kc4 + 3][nr], h.w, l.w);
        *(ushort4*)&Wth[(size_t)(n0 + nr) * 512 + k0 + kc4] = h;
        *(ushort4*)&Wtl[(size_t)(n0 + nr) * 512 + k0 + kc4] = l;
    }
}

// ---------------------------------------------------------------------------
// proj_mfma: C = X@W, split-bf16 MFMA. 128x128 tile, BK=32.
// z<2 (q,k): 3-pass split (truncated-hi A split in-kernel, W pre-split).
// z=2 (v):   1-pass hi-only (v is bf16-quantized at storage anyway).
// Outputs: q,k packed (hi<<16|lo) uint [B,H,L,D]; v ushort [B,H,D,L].
// q pre-scaled by 0.125*log2(e).
// ---------------------------------------------------------------------------
#define PSTR 40   // LDS row stride in ushorts (80 B): frag b128 reads free

__global__ __launch_bounds__(256)
void proj_mfma(const float* __restrict__ Qin, const float* __restrict__ Kin,
               const float* __restrict__ Vin, const unsigned short* __restrict__ wt,
               unsigned int* __restrict__ qhl, unsigned int* __restrict__ khl,
               unsigned short* __restrict__ vh)
{
    __shared__ unsigned short Ah[128 * PSTR], Al[128 * PSTR],
                              Bh[128 * PSTR], Bl[128 * PSTR];
    const int z = blockIdx.z;
    const bool full = (z < 2);
    const float* X = (z == 0) ? Qin : (z == 1) ? Kin : Vin;
    const unsigned short* Wth = wt + (size_t)z * 524288;
    const unsigned short* Wtl = Wth + 262144;

    const int t = threadIdx.x, lane = t & 63, w = t >> 6;
    const int wm = w & 1, wn = w >> 1;
    const int m0 = blockIdx.x * 128, n0 = blockIdx.y * 128;
    const int lm = lane & 15, lq = lane >> 4;
    const int ar = t >> 1, ak = (t & 1) * 16;

    const float* Xp = X + (size_t)(m0 + ar) * 512 + ak;
    const unsigned short* Bph = Wth + (size_t)(n0 + ar) * 512 + ak;
    const unsigned short* Bpl = Wtl + (size_t)(n0 + ar) * 512 + ak;

    f32x4 acc[4][4];
    #pragma unroll
    for (int i = 0; i < 4; ++i)
        #pragma unroll
        for (int j = 0; j < 4; ++j) acc[i][j] = 0.f;

    // prefetch k0 = 0
    float4 av[4];
    uint4 bh0, bh1, bl0, bl1;
    #pragma unroll
    for (int e = 0; e < 4; ++e) av[e] = *(const float4*)(Xp + e * 4);
    bh0 = *(const uint4*)(Bph);
    bh1 = *(const uint4*)(Bph + 8);
    if (full) { bl0 = *(const uint4*)(Bpl); bl1 = *(const uint4*)(Bpl + 8); }

    for (int k0 = 0; k0 < 512; k0 += 32) {
        __syncthreads();                       // prev iter's frag reads done
        // ---- A: truncated-hi split, 16B conflict-free writes ----
        {
            const float* ff = (const float*)&av[0];   // av[4] is contiguous
            uint hw[16];
            #pragma unroll
            for (int i = 0; i < 16; ++i) hw[i] = __float_as_uint(ff[i]) & 0xffff0000u;
            uint4 ahv  = make_uint4(__builtin_amdgcn_perm(hw[1],  hw[0],  PERM_HI),
                                    __builtin_amdgcn_perm(hw[3],  hw[2],  PERM_HI),
                                    __builtin_amdgcn_perm(hw[5],  hw[4],  PERM_HI),
                                    __builtin_amdgcn_perm(hw[7],  hw[6],  PERM_HI));
            uint4 ahv2 = make_uint4(__builtin_amdgcn_perm(hw[9],  hw[8],  PERM_HI),
                                    __builtin_amdgcn_perm(hw[11], hw[10], PERM_HI),
                                    __builtin_amdgcn_perm(hw[13], hw[12], PERM_HI),
                                    __builtin_amdgcn_perm(hw[15], hw[14], PERM_HI));
            *(uint4*)&Ah[ar * PSTR + ak]     = ahv;
            *(uint4*)&Ah[ar * PSTR + ak + 8] = ahv2;
            if (full) {
                uint lo[8];
                #pragma unroll
                for (int i = 0; i < 8; ++i) {
                    float r0 = ff[2*i]   - __uint_as_float(hw[2*i]);
                    float r1 = ff[2*i+1] - __uint_as_float(hw[2*i+1]);
                    lo[i] = ((uint)bf_hi(r1) << 16) | bf_hi(r0);
                }
                *(uint4*)&Al[ar * PSTR + ak]     = make_uint4(lo[0], lo[1], lo[2], lo[3]);
                *(uint4*)&Al[ar * PSTR + ak + 8] = make_uint4(lo[4], lo[5], lo[6], lo[7]);
            }
        }
        // ---- B: straight copies ----
        *(uint4*)&Bh[ar * PSTR + ak]     = bh0;
        *(uint4*)&Bh[ar * PSTR + ak + 8] = bh1;
        if (full) {
            *(uint4*)&Bl[ar * PSTR + ak]     = bl0;
            *(uint4*)&Bl[ar * PSTR + ak + 8] = bl1;
        }
        __syncthreads();

        if (k0 + 32 < 512) {                   // prefetch next (overlaps MFMA)
            #pragma unroll
            for (int e = 0; e < 4; ++e) av[e] = *(const float4*)(Xp + k0 + 32 + e * 4);
            bh0 = *(const uint4*)(Bph + k0 + 32);
            bh1 = *(const uint4*)(Bph + k0 + 40);
            if (full) {
                bl0 = *(const uint4*)(Bpl + k0 + 32);
                bl1 = *(const uint4*)(Bpl + k0 + 40);
            }
        }

        short8 a_h[4], a_l[4];
        #pragma unroll
        for (int mi = 0; mi < 4; ++mi) {
            int off = (wm * 64 + mi * 16 + lm) * PSTR + lq * 8;
            a_h[mi] = *(const short8*)&Ah[off];
            if (full) a_l[mi] = *(const short8*)&Al[off];
        }
        #pragma unroll
        for (int ni = 0; ni < 4; ++ni) {
            int off = (wn * 64 + ni * 16 + lm) * PSTR + lq * 8;
            short8 b_h = *(const short8*)&Bh[off];
            if (full) {
                short8 b_l = *(const short8*)&Bl[off];
                #pragma unroll
                for (int mi = 0; mi < 4; ++mi) {
                    acc[mi][ni] = MFMA16(a_l[mi], b_h, acc[mi][ni]);
                    acc[mi][ni] = MFMA16(a_h[mi], b_l, acc[mi][ni]);
                    acc[mi][ni] = MFMA16(a_h[mi], b_h, acc[mi][ni]);
                }
            } else {
                #pragma unroll
                for (int mi = 0; mi < 4; ++mi)
                    acc[mi][ni] = MFMA16(a_h[mi], b_h, acc[mi][ni]);
            }
        }
    }

    if (z < 2) {
        unsigned int* o = (z == 0) ? qhl : khl;
        const float sc = (z == 0) ? 0.18033688011112042f : 1.0f;  // 0.125*log2(e)
        #pragma unroll
        for (int mi = 0; mi < 4; ++mi)
            #pragma unroll
            for (int ni = 0; ni < 4; ++ni) {
                int n_abs = n0 + wn * 64 + ni * 16 + lm;
                int hd = n_abs >> 6, d = n_abs & 63;
                #pragma unroll
                for (int r = 0; r < 4; ++r) {
                    int m_abs = m0 + wm * 64 + mi * 16 + lq * 4 + r;
                    int b = m_abs >> 10, li = m_abs & 1023;
                    unsigned short hv, lv;
                    bf_split(acc[mi][ni][r] * sc, hv, lv);
                    o[(((size_t)b * NHEAD + hd) * LEN + li) * HDIM + d] =
                        ((unsigned)hv << 16) | lv;
                }
            }
    } else {
        #pragma unroll
        for (int mi = 0; mi < 4; ++mi) {
            int m_base = m0 + wm * 64 + mi * 16 + lq * 4;
            int b = m_base >> 10, l0 = m_base & 1023;
            #pragma unroll
            for (int ni = 0; ni < 4; ++ni) {
                int n_abs = n0 + wn * 64 + ni * 16 + lm;
                int hd = n_abs >> 6, d = n_abs & 63;
                ushort4 hv = make_ushort4(bf_hi(acc[mi][ni][0]), bf_hi(acc[mi][ni][1]),
                                          bf_hi(acc[mi][ni][2]), bf_hi(acc[mi][ni][3]));
                *(ushort4*)&vh[(((size_t)b * NHEAD + hd) * HDIM + d) * LEN + l0] = hv;
            }
        }
    }
}

// ---------------------------------------------------------------------------
// attn_mfma: causal flash attention. Block = 128 q rows (4 waves x 32).
// LDS 36.9 KB (4 blocks/CU): P aliases the K region (3rd barrier guards it).
// K staging: packed uint4 loads -> v_perm unpack -> conflict-free 16B writes.
// ---------------------------------------------------------------------------
__global__ __launch_bounds__(256)
void attn_mfma(const unsigned int* __restrict__ qhl, const unsigned int* __restrict__ khl,
               const unsigned short* __restrict__ vth, float* __restrict__ out)
{
    __shared__ unsigned short sm[18432];          // 36,864 B
    unsigned short* Kh  = sm;                     // 64*72 = 4608
    unsigned short* Kl  = sm + 4608;              // 64*72
    unsigned short* Pb  = sm;                     // 128*72 = 9216 (ALIASES Kh+Kl)
    unsigned short* Vt  = sm + 9216;              // 64*72  [d][key]
    unsigned short* Qsh = sm;                     // staging overlay
    unsigned short* Qsl = sm + 9216;

    const int t = threadIdx.x, lane = t & 63, w = t >> 6;
    const int lm = lane & 15, lq = lane >> 4;
    const int bx = blockIdx.x;
    const int qt = 7 - (bx >> 6);                 // heavy tiles dispatch first
    const int bh = bx & 63;
    const size_t base = (size_t)bh * LEN * HDIM;
    const unsigned int*   qb = qhl + base;
    const unsigned int*   kb = khl + base;
    const unsigned short* vb = vth + base;        // [d][l]
    const int Q0  = qt * 128;
    const int Q0w = Q0 + w * 32;

    // ---- stage Q (packed), pull split frags to registers ----
    #pragma unroll
    for (int e = 0; e < 8; ++e) {
        int f = e * 256 + t, r = f >> 4, c4 = (f & 15) << 2;
        uint4 u = *(const uint4*)&qb[(size_t)(Q0 + r) * 64 + c4];
        ushort4 h, l;
        unpack4(u, h, l);
        *(ushort4*)&Qsh[r * 72 + c4] = h;
        *(ushort4*)&Qsl[r * 72 + c4] = l;
    }
    __syncthreads();
    short8 qfh[2][2], qfl[2][2];
    #pragma unroll
    for (int mi = 0; mi < 2; ++mi)
        #pragma unroll
        for (int ks = 0; ks < 2; ++ks) {
            int off = (w * 32 + mi * 16 + lm) * 72 + ks * 32 + lq * 8;
            qfh[mi][ks] = *(const short8*)&Qsh[off];
            qfl[mi][ks] = *(const short8*)&Qsl[off];
        }

    float m_i[2][4], l_i[2][4];
    f32x4 oacc[2][4];
    #pragma unroll
    for (int mi = 0; mi < 2; ++mi)
        #pragma unroll
        for (int r = 0; r < 4; ++r) { m_i[mi][r] = -1e30f; l_i[mi][r] = 0.f; }
    #pragma unroll
    for (int mi = 0; mi < 2; ++mi)
        #pragma unroll
        for (int nd = 0; nd < 4; ++nd) oacc[mi][nd] = 0.f;

    // staging indices: K: row kr (0..63), d-quarter kq*16; V: d-row vd_, key seg vs8
    const int kr = t >> 2, kq = t & 3;
    const int vd_ = t >> 3, vs8 = (t & 7) << 3;

    // prefetch jb = 0
    uint4 kreg[4], vreg[2];
    #pragma unroll
    for (int e = 0; e < 4; ++e)
        kreg[e] = *(const uint4*)&kb[(size_t)kr * 64 + kq * 16 + e * 4];
    #pragma unroll
    for (int e = 0; e < 2; ++e)
        vreg[e] = *(const uint4*)&vb[(size_t)(e * 32 + vd_) * LEN + vs8];

    const int jend = 2 * qt + 1;
    for (int jb = 0; jb <= jend; ++jb) {
        __syncthreads();   // B1: prev iter's P/V/frag reads done
        {
            uint4 h0, l0, h1, l1;
            unpack8(kreg[0], kreg[1], h0, l0);
            unpack8(kreg[2], kreg[3], h1, l1);
            int ko = kr * 72 + kq * 16;
            *(uint4*)&Kh[ko]     = h0;
            *(uint4*)&Kh[ko + 8] = h1;
            *(uint4*)&Kl[ko]     = l0;
            *(uint4*)&Kl[ko + 8] = l1;
            *(uint4*)&Vt[(vd_)      * 72 + vs8] = vreg[0];
            *(uint4*)&Vt[(vd_ + 32) * 72 + vs8] = vreg[1];
        }
        __syncthreads();   // B2: staging visible

        if (jb < jend) {   // prefetch next tile; overlaps all compute below
            #pragma unroll
            for (int e = 0; e < 4; ++e)
                kreg[e] = *(const uint4*)&kb[(size_t)((jb + 1) * 64 + kr) * 64 + kq * 16 + e * 4];
            #pragma unroll
            for (int e = 0; e < 2; ++e)
                vreg[e] = *(const uint4*)&vb[(size_t)(e * 32 + vd_) * LEN + (jb + 1) * 64 + vs8];
        }

        const bool active = (jb * 64 <= Q0w + 31);
        f32x4 sf[2][4];
        if (active) {
            #pragma unroll
            for (int mi = 0; mi < 2; ++mi)
                #pragma unroll
                for (int ni = 0; ni < 4; ++ni) sf[mi][ni] = 0.f;
            #pragma unroll
            for (int ks = 0; ks < 2; ++ks)
                #pragma unroll
                for (int ni = 0; ni < 4; ++ni) {
                    int off = (ni * 16 + lm) * 72 + ks * 32 + lq * 8;
                    short8 b_h = *(const short8*)&Kh[off];
                    short8 b_l = *(const short8*)&Kl[off];
                    #pragma unroll
                    for (int mi = 0; mi < 2; ++mi) {
                        sf[mi][ni] = MFMA16(qfl[mi][ks], b_h, sf[mi][ni]);
                        sf[mi][ni] = MFMA16(qfh[mi][ks], b_l, sf[mi][ni]);
                        sf[mi][ni] = MFMA16(qfh[mi][ks], b_h, sf[mi][ni]);
                    }
                }
            if (jb * 64 + 63 > Q0w) {   // causal mask near diagonal
                #pragma unroll
                for (int mi = 0; mi < 2; ++mi)
                    #pragma unroll
                    for (int ni = 0; ni < 4; ++ni) {
                        int key = jb * 64 + ni * 16 + lm;
                        #pragma unroll
                        for (int r = 0; r < 4; ++r) {
                            int qi = Q0w + mi * 16 + lq * 4 + r;
                            if (key > qi) sf[mi][ni][r] = -1e30f;
                        }
                    }
            }
        }
        __syncthreads();   // B3: all K reads done — P may overwrite K region

        if (active) {
            // online softmax (base 2); rows on 16-lane groups -> DPP reduce
            #pragma unroll
            for (int mi = 0; mi < 2; ++mi)
                #pragma unroll
                for (int r = 0; r < 4; ++r) {
                    float mv = fmaxf(fmaxf(sf[mi][0][r], sf[mi][1][r]),
                                     fmaxf(sf[mi][2][r], sf[mi][3][r]));
                    mv = red16_max(mv);
                    float mo = m_i[mi][r];
                    float mn = fmaxf(mo, mv);
                    float al = __builtin_amdgcn_exp2f(mo - mn);
                    m_i[mi][r] = mn;
                    float rs = 0.f;
                    int prow = (w * 32 + mi * 16 + lq * 4 + r) * 72 + lm;
                    #pragma unroll
                    for (int ni = 0; ni < 4; ++ni) {
                        float p = __builtin_amdgcn_exp2f(sf[mi][ni][r] - mn);
                        rs += p;
                        Pb[prow + ni * 16] = bf_hi(p);
                    }
                    rs = red16_sum(rs);
                    l_i[mi][r] = l_i[mi][r] * al + rs;
                    #pragma unroll
                    for (int nd = 0; nd < 4; ++nd) oacc[mi][nd][r] *= al;
                }
            // P round-trip: same-wave rows, lgkmcnt ordering suffices
            short8 pf[2][2];
            #pragma unroll
            for (int mi = 0; mi < 2; ++mi)
                #pragma unroll
                for (int ks = 0; ks < 2; ++ks)
                    pf[mi][ks] = *(const short8*)&Pb[(w * 32 + mi * 16 + lm) * 72 + ks * 32 + lq * 8];
            #pragma unroll
            for (int ks = 0; ks < 2; ++ks)
                #pragma unroll
                for (int nd = 0; nd < 4; ++nd) {
                    short8 vf = *(const short8*)&Vt[(nd * 16 + lm) * 72 + ks * 32 + lq * 8];
                    #pragma unroll
                    for (int mi = 0; mi < 2; ++mi)
                        oacc[mi][nd] = MFMA16(pf[mi][ks], vf, oacc[mi][nd]);
                }
        }
    }

    // epilogue: divide by l, write [B, L, H*D] fp32
    const int b = bh >> 3, hd = bh & 7;
    #pragma unroll
    for (int mi = 0; mi < 2; ++mi)
        #pragma unroll
        for (int r = 0; r < 4; ++r) {
            int qrow = Q0w + mi * 16 + lq * 4 + r;
            float inv = 1.0f / l_i[mi][r];
            #pragma unroll
            for (int nd = 0; nd < 4; ++nd) {
                int d = nd * 16 + lm;
                out[((size_t)b * LEN + qrow) * (NHEAD * HDIM) + hd * 64 + d] =
                    oacc[mi][nd][r] * inv;
            }
        }
}

// ---------------------------------------------------------------------------
extern "C" void kernel_launch(void* const* d_in, const int* in_sizes, int n_in,
                              void* d_out, int out_size, void* d_ws, size_t ws_size,
                              hipStream_t stream)
{
    const float* Qin = (const float*)d_in[0];
    const float* Kin = (const float*)d_in[1];
    const float* Vin = (const float*)d_in[2];
    const float* WQ  = (const float*)d_in[3];
    const float* WK  = (const float*)d_in[4];
    const float* WV  = (const float*)d_in[5];

    const size_t per = (size_t)BATCH * NHEAD * LEN * HDIM;   // 4,194,304 elements
    unsigned int*   qhl = (unsigned int*)d_ws;               // 16 MB
    unsigned int*   khl = qhl + per;                         // 16 MB
    unsigned short* vh  = (unsigned short*)(khl + per);      // 8 MB
    unsigned short* wt  = vh + per;                          // 3 MB   (total 43 MB)

    wprep    <<<dim3(8, 8, 3),  256, 0, stream>>>(WQ, WK, WV, wt);
    proj_mfma<<<dim3(64, 4, 3), 256, 0, stream>>>(Qin, Kin, Vin, wt, qhl, khl, vh);
    attn_mfma<<<dim3(512),      256, 0, stream>>>(qhl, khl, vh, (float*)d_out);
}